// Round 7
// baseline (118.400 us; speedup 1.0000x reference)
//
#include <hip/hip_runtime.h>

#define Bn 16
#define Hn 128
#define Wn 8192
#define NMAX 64
#define HALF 4096              // output columns per window (2 windows/row)

// =====================================================================
// R16 = R14 structure with HALF-ROW OUTPUT WINDOWS (occupancy 2x).
// R14 post-mortem: total 114.8 (best). Fills 41.3-41.7 (cached-store
// dirty-L3 effect confirmed, banked). Kernel+gaps ~31.7us vs 14.2us
// traffic floor. Remaining unexamined lever INSIDE the winning LDS
// structure: 32KB LDS -> only 4 blocks/CU (16 waves) and a full-block
// barrier with little cover. This version: each block owns a 4096-col
// output window (16KB LDS) -> 4096 blocks, 8 blocks/CU, 32 waves/CU.
// Same proven phases: predicated per-segment contiguous loads (full
// MLP) -> LDS scatter (2-way aliasing free) -> tail zero -> aligned
// cached float4 stores. Straddling segments load in both windows
// (~216B/row extra, negligible).
// LEDGER (do not re-attempt):
//  R9:  pair-load PASS1 + tail-bypass stores  -> +2.9us.
//  R10: per-segment rect scatter, no LDS      -> 44us kernel.
//  R11: R10 + MLP=32                          -> 40us. MLP not binding.
//  R12: uniform tile gather + NT f4           -> 39.5us.
//  R13: R12 + cached stores + coalesced loads -> 37.9us.
//  => no-LDS structures plateau 38-44us; LDS row-image ~27-32us.
//  R14: cached final stores -> fills 44.5->41.5 each (banked; keep).
// =====================================================================
__global__ __launch_bounds__(256) void row_pack_win_kernel(
    const float* __restrict__ x, const int* __restrict__ xi,
    const int* __restrict__ N, const float* __restrict__ sep_param,
    float* __restrict__ out, float* __restrict__ out_xi) {
    __shared__ float s_half[HALF];       // 16 KB window image
    __shared__ int s_start[NMAX];
    __shared__ int s_w[NMAX];
    __shared__ int s_src0[NMAX];
    __shared__ int s_n, s_tail, s_wide;

    const int win  = blockIdx.x;         // 0..4095
    const int row  = win >> 1;           // b*H + h  (C==1)
    const int half = win & 1;
    const int b    = row >> 7;
    const int W0   = half * HALF;        // window start column
    const int tid  = threadIdx.x;

    if (tid < NMAX) {                    // wave 0: 64-lane width scan
        int nb = N[b];
        int s0 = xi[(b * NMAX + tid) * 2 + 0];
        int s1 = xi[(b * NMAX + tid) * 2 + 1];
        int w = s1 - s0; if (w < 0) w = 0;
        bool valid = tid < nb;
        int wv = valid ? w : 0;
        int c = wv;
        #pragma unroll
        for (int d = 1; d < 64; d <<= 1) {
            int t = __shfl_up(c, d, 64);
            if (tid >= d) c += t;
        }
        int start_new = c - wv + tid;
        int end_new   = c + tid;
        s_start[tid] = start_new;
        s_w[tid]     = wv;
        s_src0[tid]  = s0;
        unsigned long long wide = __ballot(wv > 127);
        if (tid == 0) {
            s_n = nb;
            s_wide = (wide != 0ULL) ? 1 : 0;
        }
        int last = (nb > 0) ? (nb - 1) : 0;
        if (tid == last) s_tail = (nb > 0) ? end_new : 0;
        if ((row & 127) == 0 && half == 0) {   // fused xi_new (16 writer blocks)
            out_xi[(b * NMAX + tid) * 2 + 0] = valid ? (float)start_new : 0.0f;
            out_xi[(b * NMAX + tid) * 2 + 1] = valid ? (float)end_new : 0.0f;
        }
    }
    __syncthreads();

    const int nb   = s_n;
    const int tail = s_tail;
    const float sep = sep_param[0];
    const float* __restrict__ xrow = x + (size_t)row * Wn;
    float* __restrict__ orow = out + (size_t)row * Wn + W0;
    const int wave = tid >> 6;
    const int lane = tid & 63;

    // ---- PASS 1: issue all loads for segments intersecting the window ----
    float v0[16], v1[16];
    int sg_base[16], sg_lo[16], sg_hi[16];
    #pragma unroll
    for (int k = 0; k < 16; ++k) {
        const int seg = wave + 4 * k;
        const bool act = seg < nb;
        const int s    = act ? s_start[seg] : 0;
        const int w    = act ? s_w[seg] : 0;
        const int src0 = act ? s_src0[seg] : 0;
        const int wt   = act ? (w + ((seg < nb - 1) ? 1 : 0)) : 0;
        const int base = s - W0;                    // LDS pos of seg start
        int lo = -base; if (lo < 0) lo = 0;         // first l inside window
        int hi = HALF - base; if (hi > wt) hi = wt; // one past last l
        sg_base[k] = base;
        sg_lo[k]   = lo;
        sg_hi[k]   = hi;
        const bool d0 = (lane >= lo) && (lane < hi) && (lane < w);
        const bool d1 = (lane + 64 >= lo) && (lane + 64 < hi) && (lane + 64 < w);
        v0[k] = d0 ? xrow[src0 + lane]      : sep;
        v1[k] = d1 ? xrow[src0 + lane + 64] : sep;
    }

    // ---- PASS 2: scatter into LDS window image (2-way aliasing = free) ----
    #pragma unroll
    for (int k = 0; k < 16; ++k) {
        const int l0 = lane, l1 = lane + 64;
        if (l0 >= sg_lo[k] && l0 < sg_hi[k]) s_half[sg_base[k] + l0] = v0[k];
        if (l1 >= sg_lo[k] && l1 < sg_hi[k]) s_half[sg_base[k] + l1] = v1[k];
    }

    // ---- rare fallback for segments wider than 128 (never in practice) ----
    if (s_wide) {
        for (int seg = wave; seg < nb; seg += 4) {
            const int w = s_w[seg];
            const int wt = w + ((seg < nb - 1) ? 1 : 0);
            const int base = s_start[seg] - W0;
            for (int l = 128 + lane; l < wt; l += 64) {
                const int p = base + l;
                if (p >= 0 && p < HALF) s_half[p] = (l < w) ? xrow[s_src0[seg] + l] : sep;
            }
        }
    }

    // ---- zero LDS tail: window-relative [twin, HALF) ----
    int twin = tail - W0;
    if (twin < 0) twin = 0; if (twin > HALF) twin = HALF;
    const int t4 = (twin + 3) & ~3;
    if (tid < (t4 - twin)) s_half[twin + tid] = 0.0f;   // <=3 threads
    float4* s_half4 = reinterpret_cast<float4*>(s_half);
    const float4 z4 = make_float4(0.0f, 0.0f, 0.0f, 0.0f);
    for (int i4 = (t4 >> 2) + tid; i4 < (HALF >> 2); i4 += 256) {
        s_half4[i4] = z4;
    }
    __syncthreads();

    // ---- FINAL: aligned CACHED float4 window store (4/thread) ----
    float4* orow4 = reinterpret_cast<float4*>(orow);
    #pragma unroll
    for (int g = 0; g < 4; ++g) {
        orow4[g * 256 + tid] = s_half4[g * 256 + tid];
    }
}

extern "C" void kernel_launch(void* const* d_in, const int* in_sizes, int n_in,
                              void* d_out, int out_size, void* d_ws, size_t ws_size,
                              hipStream_t stream) {
    const float* x   = (const float*)d_in[0];
    const int* xi    = (const int*)d_in[1];
    const int* N     = (const int*)d_in[2];
    const float* sep = (const float*)d_in[3];

    float* out_x  = (float*)d_out;
    float* out_xi = (float*)d_out + (size_t)Bn * Hn * Wn;

    row_pack_win_kernel<<<Bn * Hn * 2, 256, 0, stream>>>(x, xi, N, sep, out_x, out_xi);
}

// Round 8
// 115.125 us; speedup vs baseline: 1.0284x; 1.0284x over previous
//
#include <hip/hip_runtime.h>

#define Bn 16
#define Hn 128
#define Wn 8192
#define NMAX 64

typedef float nt_f4 __attribute__((ext_vector_type(4)));  // native vec for nontemporal builtin

// =====================================================================
// R17 = R14 base + BLOCK-UNIFORM split store: cached for data groups,
// direct NT zeros for the all-zero tail groups (no LDS round-trip).
// Model (validated by R10 exact decomposition: total = 2 fills + kernel):
//   R8-NT kernel 26.5 + fills 44.5x2 = 114.5
//   R14-cached  kernel 31.7 + fills 41.5x2 = 114.8
// -> the 64MB output crosses the expensive path once/iter either way:
//    NT pays HBM-write in-kernel; cached pays a SLOWER L2->L3 eviction
//    path in-kernel but refunds ~6us on fills (in-cache overwrite). H6.
// Exploit: ~63% of output (zero tail, ~40MB) gains nothing from being
// dirty-in-L3. Store it NT directly (no LDS read, no LDS zeroing);
// keep cached LDS stores for the ~24MB data region (keeps most of the
// fill refund). Branch is per float4-GROUP (g*1024 vs zend), uniform
// across the block -> zero divergence (R9's failure mode avoided).
// LEDGER (do not re-attempt):
//  R9:  pair-load PASS1 + PER-THREAD tail-bypass -> +2.9us (divergence).
//  R10: per-segment rect scatter, no LDS      -> 44us kernel.
//  R11: R10 + MLP=32                          -> 40us. MLP not binding.
//  R12: uniform tile gather + NT f4           -> 39.5us.
//  R13: R12 + cached stores + coalesced loads -> 37.9us.
//  R16: half-row windows (2x occupancy)       -> 35.2us. occupancy not
//       binding; scan duplication costs.
//  => LDS row-image structure stands. R14 cached-store fill refund
//     banked (fills 44.5 -> 41.5 each).
// Pre-commit: total >= 113 -> restore R14, declare practical ceiling.
// =====================================================================
__global__ __launch_bounds__(256) void row_pack_lds_kernel(
    const float* __restrict__ x, const int* __restrict__ xi,
    const int* __restrict__ N, const float* __restrict__ sep_param,
    float* __restrict__ out, float* __restrict__ out_xi) {
    __shared__ float s_row[Wn];          // 32 KB row image
    __shared__ int s_start[NMAX];
    __shared__ int s_w[NMAX];
    __shared__ int s_src0[NMAX];
    __shared__ int s_n, s_tail, s_wide;

    const int row = blockIdx.x;          // b*H + h  (C==1)
    const int b   = row >> 7;
    const int tid = threadIdx.x;

    if (tid < NMAX) {                    // wave 0: 64-lane width scan
        int nb = N[b];
        int s0 = xi[(b * NMAX + tid) * 2 + 0];
        int s1 = xi[(b * NMAX + tid) * 2 + 1];
        int w = s1 - s0; if (w < 0) w = 0;
        bool valid = tid < nb;
        int wv = valid ? w : 0;
        int c = wv;
        #pragma unroll
        for (int d = 1; d < 64; d <<= 1) {
            int t = __shfl_up(c, d, 64);
            if (tid >= d) c += t;
        }
        int start_new = c - wv + tid;
        int end_new   = c + tid;
        s_start[tid] = start_new;
        s_w[tid]     = wv;
        s_src0[tid]  = s0;
        unsigned long long wide = __ballot(wv > 127);
        if (tid == 0) {
            s_n = nb;
            s_wide = (wide != 0ULL) ? 1 : 0;
        }
        int last = (nb > 0) ? (nb - 1) : 0;
        if (tid == last) s_tail = (nb > 0) ? end_new : 0;
        if ((row & 127) == 0) {          // fused xi_new (16 writer blocks)
            out_xi[(b * NMAX + tid) * 2 + 0] = valid ? (float)start_new : 0.0f;
            out_xi[(b * NMAX + tid) * 2 + 1] = valid ? (float)end_new : 0.0f;
        }
    }
    __syncthreads();

    const int nb   = s_n;
    const int tail = s_tail;
    const float sep = sep_param[0];
    const float* __restrict__ xrow = x + (size_t)row * Wn;
    float* __restrict__ orow = out + (size_t)row * Wn;
    const int wave = tid >> 6;
    const int lane = tid & 63;

    // ---- PASS 1: issue ALL global loads (independent, predicated) ----
    float v0[16], v1[16];
    int sg_s[16], sg_wt[16];
    #pragma unroll
    for (int k = 0; k < 16; ++k) {
        const int seg = wave + 4 * k;
        const bool act = seg < nb;
        const int s    = act ? s_start[seg] : 0;
        const int w    = act ? s_w[seg] : 0;
        const int src0 = act ? s_src0[seg] : 0;
        sg_s[k]  = s;
        sg_wt[k] = act ? (w + ((seg < nb - 1) ? 1 : 0)) : 0;
        v0[k] = (lane < w)      ? xrow[src0 + lane]      : sep;
        v1[k] = (lane + 64 < w) ? xrow[src0 + lane + 64] : sep;
    }

    // ---- PASS 2: scatter into LDS row image (2-way aliasing = free) ----
    #pragma unroll
    for (int k = 0; k < 16; ++k) {
        if (lane < sg_wt[k])      s_row[sg_s[k] + lane]      = v0[k];
        if (lane + 64 < sg_wt[k]) s_row[sg_s[k] + lane + 64] = v1[k];
    }

    // ---- rare fallback for segments wider than 128 (never in practice) ----
    if (s_wide) {
        for (int seg = wave; seg < nb; seg += 4) {
            const int w = s_w[seg];
            const int wtot = w + ((seg < nb - 1) ? 1 : 0);
            for (int l = 128 + lane; l < wtot; l += 64) {
                s_row[s_start[seg] + l] = (l < w) ? xrow[s_src0[seg] + l] : sep;
            }
        }
    }

    // ---- store-group geometry (block-uniform): groups of 1024 cols ----
    const int gb   = tail >> 10;                 // boundary group index
    int zend = (gb + 1) << 10;                   // end col of boundary group
    if (zend > Wn) zend = Wn;

    // ---- NT-zero stores for fully-zero groups (no LDS dependency) ----
    nt_f4* orow4n = reinterpret_cast<nt_f4*>(orow);
    const nt_f4 zn = {0.0f, 0.0f, 0.0f, 0.0f};
    #pragma unroll
    for (int g = 0; g < 8; ++g) {
        if ((g << 10) >= zend) {                 // uniform across block
            __builtin_nontemporal_store(zn, orow4n + g * 256 + tid);
        }
    }

    // ---- zero LDS only through the boundary group [tail, zend) ----
    const int t4 = (tail + 3) & ~3;
    if (tid < (t4 - tail)) s_row[tail + tid] = 0.0f;    // <=3 threads
    float4* s_row4 = reinterpret_cast<float4*>(s_row);
    const float4 z4 = make_float4(0.0f, 0.0f, 0.0f, 0.0f);
    for (int i4 = (t4 >> 2) + tid; i4 < (zend >> 2); i4 += 256) {
        s_row4[i4] = z4;
    }
    __syncthreads();

    // ---- FINAL: cached float4 stores for data/boundary groups ----
    float4* orow4 = reinterpret_cast<float4*>(orow);
    #pragma unroll
    for (int g = 0; g < 8; ++g) {
        if ((g << 10) < zend) {                  // uniform across block
            orow4[g * 256 + tid] = s_row4[g * 256 + tid];
        }
    }
}

extern "C" void kernel_launch(void* const* d_in, const int* in_sizes, int n_in,
                              void* d_out, int out_size, void* d_ws, size_t ws_size,
                              hipStream_t stream) {
    const float* x   = (const float*)d_in[0];
    const int* xi    = (const int*)d_in[1];
    const int* N     = (const int*)d_in[2];
    const float* sep = (const float*)d_in[3];

    float* out_x  = (float*)d_out;
    float* out_xi = (float*)d_out + (size_t)Bn * Hn * Wn;

    row_pack_lds_kernel<<<Bn * Hn, 256, 0, stream>>>(x, xi, N, sep, out_x, out_xi);
}